// Round 2
// 1725.609 us; speedup vs baseline: 8.8578x; 8.8578x over previous
//
#include <hip/hip_runtime.h>
#include <math.h>

#define Bn  16
#define Sn  626
#define Dn  768
#define Hn  12
#define HDn 64
#define Mn  (Bn*Sn)        // 10016
#define BHn (Bn*Hn)        // 192

#define QT   16
#define KT2  64
#define SPAD 628

// workspace float offsets
#define WS_TENSOR ((size_t)Bn*Sn*Dn)        // 7,692,288 floats each
#define Q_OFF   ((size_t)0)
#define K_OFF   (WS_TENSOR)
#define V_OFF   (2*WS_TENSOR)
#define CTX_OFF (3*WS_TENSOR)
#define COL_OFF (4*WS_TENSOR)

// output element offsets (fp32 elements), concatenated in return order:
// attention_output (16,626,768) | attention_probs (16,12,626,626) | contribution (16,12,626)
#define OUT1_OFF ((size_t)Bn*Sn*Dn)                      // attention_probs
#define OUT2_OFF (OUT1_OFF + (size_t)BHn*Sn*Sn)          // contribution

// ---------------------------------------------------------------------------
// Kernel 1: fused QKV projection.  C = hidden(M x 768) @ W(768 x 768) + b,
// fp32 in, fp32 accumulate, stored to ws in (b, h, s, hd) fp32 layout.
// ---------------------------------------------------------------------------
__global__ __launch_bounds__(256) void qkv_gemm(
    const float* __restrict__ A,
    const float* __restrict__ Wq, const float* __restrict__ bq,
    const float* __restrict__ Wk, const float* __restrict__ bk,
    const float* __restrict__ Wv, const float* __restrict__ bv,
    float* __restrict__ ws)
{
    __shared__ float As[8][128];   // transposed: As[k][m]
    __shared__ float Bs[8][128];

    const int z = blockIdx.z;
    const float* __restrict__ W    = (z == 0) ? Wq : (z == 1) ? Wk : Wv;
    const float* __restrict__ bias = (z == 0) ? bq : (z == 1) ? bk : bv;
    float* __restrict__ out = ws + (size_t)z * WS_TENSOR;

    const int m0 = blockIdx.x * 128;
    const int n0 = blockIdx.y * 128;
    const int t  = threadIdx.x;
    const int tx = t & 15;
    const int ty = t >> 4;

    float acc[8][8];
#pragma unroll
    for (int i = 0; i < 8; ++i)
#pragma unroll
        for (int j = 0; j < 8; ++j) acc[i][j] = 0.f;

    const int a_m = t >> 1;
    const int a_k = (t & 1) * 4;
    const int b_k = t >> 5;
    const int b_n = (t & 31) * 4;
    const int arow = m0 + a_m;

    for (int k0 = 0; k0 < Dn; k0 += 8) {
        float4 av = make_float4(0.f, 0.f, 0.f, 0.f);
        if (arow < Mn) av = *(const float4*)(A + (size_t)arow*Dn + k0 + a_k);
        As[a_k+0][a_m] = av.x;
        As[a_k+1][a_m] = av.y;
        As[a_k+2][a_m] = av.z;
        As[a_k+3][a_m] = av.w;
        *(float4*)&Bs[b_k][b_n] =
            *(const float4*)(W + (size_t)(k0 + b_k)*Dn + n0 + b_n);
        __syncthreads();
#pragma unroll
        for (int kk = 0; kk < 8; ++kk) {
            float a[8], b[8];
            *(float4*)&a[0] = *(const float4*)&As[kk][ty*4];
            *(float4*)&a[4] = *(const float4*)&As[kk][64 + ty*4];
            *(float4*)&b[0] = *(const float4*)&Bs[kk][tx*4];
            *(float4*)&b[4] = *(const float4*)&Bs[kk][64 + tx*4];
#pragma unroll
            for (int i = 0; i < 8; ++i)
#pragma unroll
                for (int j = 0; j < 8; ++j)
                    acc[i][j] += a[i]*b[j];
        }
        __syncthreads();
    }

#pragma unroll
    for (int i = 0; i < 8; ++i) {
        int ml = (i < 4) ? (ty*4 + i) : (64 + ty*4 + i - 4);
        int m = m0 + ml;
        if (m >= Mn) continue;
        int bb = m / Sn;
        int s  = m - bb*Sn;
#pragma unroll
        for (int jg = 0; jg < 2; ++jg) {
            int nl = (jg == 0) ? (tx*4) : (64 + tx*4);
            int n  = n0 + nl;
            int h  = n >> 6;
            int hd = n & 63;
            float4 r;
            r.x = acc[i][jg*4+0] + bias[n+0];
            r.y = acc[i][jg*4+1] + bias[n+1];
            r.z = acc[i][jg*4+2] + bias[n+2];
            r.w = acc[i][jg*4+3] + bias[n+3];
            *(float4*)(out + (((size_t)(bb*Hn + h)*Sn + s)*HDn + hd)) = r;
        }
    }
}

// ---------------------------------------------------------------------------
// Kernel 2: attention core.  One block = one (b,h) x 16 query rows.
// VGPR-capped at 128 (launch_bounds 256,2 -> 2 blocks/CU), bounded unrolls
// (no scratch spill), register-resident softmax, coalesced float2 probs
// writes.  Staging: each thread loads 16 floats (full 64x64 tile with 256
// threads) using the proven t>>3 / (t&7)*8 pattern looped over both halves.
// ---------------------------------------------------------------------------
__global__ __launch_bounds__(256, 2) void attn_kernel(
    const float* __restrict__ qws, const float* __restrict__ kws,
    const float* __restrict__ vws, const int* __restrict__ mask,
    float* __restrict__ probs_out,
    float* __restrict__ ctxws, float* __restrict__ colws)
{
    __shared__ float sc[QT][SPAD];   // 16 x 628 scores -> probs (40.2 KB)
    __shared__ float qs[QT][68];     // Q tile (4.3 KB)
    __shared__ float ks[KT2][68];    // K tile, reused for V tile (17.4 KB)
    __shared__ float red[256];       // row-0 fix reduction (1 KB)

    const int bh = blockIdx.y;
    const int bb = bh / Hn;
    const int q0 = blockIdx.x * QT;
    const int t  = threadIdx.x;

    // stage Q tile (zero-padded rows beyond S)
    {
        int r = t >> 4;
        int d = (t & 15) * 4;
        int q = q0 + r;
        float4 v = make_float4(0.f, 0.f, 0.f, 0.f);
        if (q < Sn) v = *(const float4*)(qws + ((size_t)bh*Sn + q)*HDn + d);
        *(float4*)&qs[r][d] = v;
    }
    __syncthreads();

    // ---- phase 1: scores = Q K^T / 8 ------------------------------------
    // compute thread -> (row group rg: 4 rows, key 0..63). 64-key tiles.
    const int rg  = (t >> 5) & 3;                 // rows 4*rg .. 4*rg+3
    const int key = (t & 31) | ((t >> 2) & 32);   // 0..63
    // staging thread -> 16 floats: rows {t>>3, 32 + t>>3}, cols (t&7)*8 +0..7
    const int ski = t >> 3;        // 0..31
    const int skd = (t & 7) * 8;   // 0..56

    for (int kc = 0; kc < Sn; kc += KT2) {
        int csz = min(KT2, Sn - kc);
#pragma unroll
        for (int rr = 0; rr < KT2; rr += 32) {
            int row = rr + ski;
            float4 v0 = make_float4(0.f, 0.f, 0.f, 0.f);
            float4 v1 = v0;
            if (row < csz) {
                const float* src = kws + ((size_t)bh*Sn + kc + row)*HDn + skd;
                v0 = *(const float4*)(src);
                v1 = *(const float4*)(src + 4);
            }
            *(float4*)&ks[row][skd]     = v0;
            *(float4*)&ks[row][skd + 4] = v1;
        }
        __syncthreads();
        if (key < csz) {
            const float4* kr  = (const float4*)&ks[key][0];
            const float4* qp0 = (const float4*)&qs[rg*4+0][0];
            const float4* qp1 = (const float4*)&qs[rg*4+1][0];
            const float4* qp2 = (const float4*)&qs[rg*4+2][0];
            const float4* qp3 = (const float4*)&qs[rg*4+3][0];
            float s0 = 0.f, s1 = 0.f, s2 = 0.f, s3 = 0.f;
#pragma unroll 4
            for (int d4 = 0; d4 < 16; ++d4) {
                float4 kv = kr[d4];
                float4 a0 = qp0[d4];
                float4 a1 = qp1[d4];
                float4 a2 = qp2[d4];
                float4 a3 = qp3[d4];
                s0 += a0.x*kv.x + a0.y*kv.y + a0.z*kv.z + a0.w*kv.w;
                s1 += a1.x*kv.x + a1.y*kv.y + a1.z*kv.z + a1.w*kv.w;
                s2 += a2.x*kv.x + a2.y*kv.y + a2.z*kv.z + a2.w*kv.w;
                s3 += a3.x*kv.x + a3.y*kv.y + a3.z*kv.z + a3.w*kv.w;
            }
            sc[rg*4+0][kc+key] = s0 * 0.125f;
            sc[rg*4+1][kc+key] = s1 * 0.125f;
            sc[rg*4+2][kc+key] = s2 * 0.125f;
            sc[rg*4+3][kc+key] = s3 * 0.125f;
        }
        __syncthreads();
    }

    // ---- phase 2: row-0 adjustment (global q==0 lives in q-tile 0) ------
    // max_as computed BEFORE modification; add max*0.25 where mask626==0.
    if (blockIdx.x == 0) {
        float lm = -INFINITY;
        for (int k = t; k < Sn; k += 256) lm = fmaxf(lm, sc[0][k]);
        red[t] = lm;
        __syncthreads();
        for (int off = 128; off > 0; off >>= 1) {
            if (t < off) red[t] = fmaxf(red[t], red[t + off]);
            __syncthreads();
        }
        float addv = red[0] * 0.25f;   // COEFF_MAX
        for (int k = t; k < Sn; k += 256) {
            int mz = (k == 0) ? 0 : mask[(size_t)bb*(Sn-1) + k - 1];
            if (mz == 0) sc[0][k] += addv;
        }
        __syncthreads();
    }

    // col-0 extraction (post row-0 fix, pre softmax) for contribution
    if (t < QT) {
        int q = q0 + t;
        if (q < Sn) colws[(size_t)bh*Sn + q] = sc[t][0];
    }
    __syncthreads();

    // ---- phase 3: row softmax, register-resident --------------------------
    // row r handled by 16 threads; each thread holds 20 float2 (40 elems).
    const int r = t >> 4;
    const int j = t & 15;
    const int q = q0 + r;
    {
        float2 rv[20];
        float lm = -INFINITY;
#pragma unroll
        for (int i = 0; i < 20; ++i) {
            int c = j*2 + i*32;
            float2 v = make_float2(-INFINITY, -INFINITY);
            if (c < Sn) v = *(const float2*)&sc[r][c];
            rv[i] = v;
            lm = fmaxf(lm, fmaxf(v.x, v.y));
        }
#pragma unroll
        for (int m = 8; m > 0; m >>= 1)
            lm = fmaxf(lm, __shfl_xor(lm, m, 16));

        float ls = 0.f;
#pragma unroll
        for (int i = 0; i < 20; ++i) {
            float ex = expf(rv[i].x - lm);
            float ey = expf(rv[i].y - lm);
            rv[i] = make_float2(ex, ey);
            ls += ex + ey;
        }
#pragma unroll
        for (int m = 8; m > 0; m >>= 1)
            ls += __shfl_xor(ls, m, 16);

        float inv = 1.0f / ls;
        float* orow = probs_out + ((size_t)bh*Sn + q)*Sn;
#pragma unroll
        for (int i = 0; i < 20; ++i) {
            int c = j*2 + i*32;
            if (c < Sn) {
                float2 p = make_float2(rv[i].x * inv, rv[i].y * inv);
                *(float2*)&sc[r][c] = p;            // probs for PV
                if (q < Sn) *(float2*)&orow[c] = p; // coalesced 128B chunks
            }
        }
    }
    __syncthreads();

    // ---- phase 4: ctx = P @ V  (thread: row r, cols j*4..j*4+3) ----------
    float4 accv = make_float4(0.f, 0.f, 0.f, 0.f);
    for (int kc = 0; kc < Sn; kc += KT2) {
        int csz = min(KT2, Sn - kc);   // 64 or 50 (always even)
#pragma unroll
        for (int rr = 0; rr < KT2; rr += 32) {
            int row = rr + ski;
            float4 v0 = make_float4(0.f, 0.f, 0.f, 0.f);
            float4 v1 = v0;
            if (row < csz) {
                const float* src = vws + ((size_t)bh*Sn + kc + row)*HDn + skd;
                v0 = *(const float4*)(src);
                v1 = *(const float4*)(src + 4);
            }
            *(float4*)&ks[row][skd]     = v0;   // zero-fill pad rows (no NaN)
            *(float4*)&ks[row][skd + 4] = v1;
        }
        __syncthreads();
#pragma unroll 2
        for (int kk = 0; kk < csz; kk += 2) {
            float2 p2 = *(const float2*)&sc[r][kc + kk];
            float4 v0 = *(const float4*)&ks[kk][j*4];
            float4 v1 = *(const float4*)&ks[kk+1][j*4];
            accv.x += p2.x*v0.x + p2.y*v1.x;
            accv.y += p2.x*v0.y + p2.y*v1.y;
            accv.z += p2.x*v0.z + p2.y*v1.z;
            accv.w += p2.x*v0.w + p2.y*v1.w;
        }
        __syncthreads();
    }
    if (q < Sn)
        *(float4*)(ctxws + ((size_t)bh*Sn + q)*HDn + j*4) = accv;
}

// ---------------------------------------------------------------------------
// Kernel 3: contribution = softmax over q of scores[:,:,q,0]
// ---------------------------------------------------------------------------
__global__ __launch_bounds__(256) void contrib_kernel(
    const float* __restrict__ colws, float* __restrict__ out2)
{
    __shared__ float red[256];
    const int bh = blockIdx.x;
    const int t  = threadIdx.x;
    const float* col = colws + (size_t)bh*Sn;

    float lm = -INFINITY;
    for (int q = t; q < Sn; q += 256) lm = fmaxf(lm, col[q]);
    red[t] = lm;
    __syncthreads();
    for (int off = 128; off > 0; off >>= 1) {
        if (t < off) red[t] = fmaxf(red[t], red[t + off]);
        __syncthreads();
    }
    float mx = red[0];
    __syncthreads();
    float ls = 0.f;
    for (int q = t; q < Sn; q += 256) ls += expf(col[q] - mx);
    red[t] = ls;
    __syncthreads();
    for (int off = 128; off > 0; off >>= 1) {
        if (t < off) red[t] += red[t + off];
        __syncthreads();
    }
    float inv = 1.0f / red[0];
    for (int q = t; q < Sn; q += 256)
        out2[(size_t)bh*Sn + q] = expf(col[q] - mx) * inv;
}

// ---------------------------------------------------------------------------
// Kernel 4: attention_output = ctx @ Wo + bo  (fp32 in, fp32 out)
// ---------------------------------------------------------------------------
__global__ __launch_bounds__(256) void out_gemm(
    const float* __restrict__ ctx,
    const float* __restrict__ Wo, const float* __restrict__ bo,
    float* __restrict__ out0)
{
    __shared__ float As[8][128];
    __shared__ float Bs[8][128];

    const int m0 = blockIdx.x * 128;
    const int n0 = blockIdx.y * 128;
    const int t  = threadIdx.x;
    const int tx = t & 15;
    const int ty = t >> 4;

    float acc[8][8];
#pragma unroll
    for (int i = 0; i < 8; ++i)
#pragma unroll
        for (int j = 0; j < 8; ++j) acc[i][j] = 0.f;

    const int a_m = t >> 1;
    const int a_k = (t & 1) * 4;
    const int b_k = t >> 5;
    const int b_n = (t & 31) * 4;
    const int arow = m0 + a_m;
    int bb = 0, s = 0;
    if (arow < Mn) { bb = arow / Sn; s = arow - bb*Sn; }

    for (int k0 = 0; k0 < Dn; k0 += 8) {
        float4 av = make_float4(0.f, 0.f, 0.f, 0.f);
        if (arow < Mn) {
            int k = k0 + a_k;
            av = *(const float4*)(ctx +
                 (((size_t)(bb*Hn + (k >> 6))*Sn + s)*HDn + (k & 63)));
        }
        As[a_k+0][a_m] = av.x;
        As[a_k+1][a_m] = av.y;
        As[a_k+2][a_m] = av.z;
        As[a_k+3][a_m] = av.w;
        *(float4*)&Bs[b_k][b_n] =
            *(const float4*)(Wo + (size_t)(k0 + b_k)*Dn + n0 + b_n);
        __syncthreads();
#pragma unroll
        for (int kk = 0; kk < 8; ++kk) {
            float a[8], b[8];
            *(float4*)&a[0] = *(const float4*)&As[kk][ty*4];
            *(float4*)&a[4] = *(const float4*)&As[kk][64 + ty*4];
            *(float4*)&b[0] = *(const float4*)&Bs[kk][tx*4];
            *(float4*)&b[4] = *(const float4*)&Bs[kk][64 + tx*4];
#pragma unroll
            for (int i = 0; i < 8; ++i)
#pragma unroll
                for (int j = 0; j < 8; ++j)
                    acc[i][j] += a[i]*b[j];
        }
        __syncthreads();
    }

#pragma unroll
    for (int i = 0; i < 8; ++i) {
        int ml = (i < 4) ? (ty*4 + i) : (64 + ty*4 + i - 4);
        int m = m0 + ml;
        if (m >= Mn) continue;
#pragma unroll
        for (int jg = 0; jg < 2; ++jg) {
            int nl = (jg == 0) ? (tx*4) : (64 + tx*4);
            int n  = n0 + nl;
            float4 r;
            r.x = acc[i][jg*4+0] + bo[n+0];
            r.y = acc[i][jg*4+1] + bo[n+1];
            r.z = acc[i][jg*4+2] + bo[n+2];
            r.w = acc[i][jg*4+3] + bo[n+3];
            *(float4*)(out0 + (size_t)m*Dn + n) = r;
        }
    }
}

// ---------------------------------------------------------------------------
extern "C" void kernel_launch(void* const* d_in, const int* in_sizes, int n_in,
                              void* d_out, int out_size, void* d_ws, size_t ws_size,
                              hipStream_t stream)
{
    (void)in_sizes; (void)n_in; (void)out_size; (void)ws_size;
    const float* hidden = (const float*)d_in[0];
    const int*   mask   = (const int*)d_in[1];
    const float* Wq = (const float*)d_in[2];
    const float* bq = (const float*)d_in[3];
    const float* Wk = (const float*)d_in[4];
    const float* bk = (const float*)d_in[5];
    const float* Wv = (const float*)d_in[6];
    const float* bv = (const float*)d_in[7];
    const float* Wo = (const float*)d_in[8];
    const float* bo = (const float*)d_in[9];

    float* ws  = (float*)d_ws;
    float* out = (float*)d_out;

    float* qws   = ws + Q_OFF;
    float* kws   = ws + K_OFF;
    float* vws   = ws + V_OFF;
    float* ctxws = ws + CTX_OFF;
    float* colws = ws + COL_OFF;

    qkv_gemm<<<dim3((Mn + 127)/128, Dn/128, 3), 256, 0, stream>>>(
        hidden, Wq, bq, Wk, bk, Wv, bv, ws);

    attn_kernel<<<dim3((Sn + QT - 1)/QT, BHn), 256, 0, stream>>>(
        qws, kws, vws, mask, out + OUT1_OFF, ctxws, colws);

    contrib_kernel<<<BHn, 256, 0, stream>>>(colws, out + OUT2_OFF);

    out_gemm<<<dim3((Mn + 127)/128, Dn/128), 256, 0, stream>>>(
        ctxws, Wo, bo, out);
}

// Round 4
// 1260.920 us; speedup vs baseline: 12.1222x; 1.3685x over previous
//
#include <hip/hip_runtime.h>
#include <math.h>

#define Bn  16
#define Sn  626
#define Dn  768
#define Hn  12
#define HDn 64
#define Mn  (Bn*Sn)        // 10016
#define BHn (Bn*Hn)        // 192

#define QT   16
#define SPAD 644           // score tile column pad (>= 640, float4-aligned rows)
#define VTS  632           // V^T row stride in ushorts (>=626, 16B-aligned rows)

// ---------------- workspace layout (float offsets) -------------------------
// Q   f32 [bh][s][64]            : WS_TENSOR floats at 0
// CTX f32 [bh][s][64]            : WS_TENSOR floats at WS_TENSOR
// then ushort arrays (based at ws + 2*WS_TENSOR):
//   kh  bf16-hi [bh][s][64]      : KV_ELEMS ushorts
//   kl  bf16-lo [bh][s][64]      : KV_ELEMS ushorts
//   vth bf16-hi [bh][d][VTS]     : VT_ELEMS ushorts   (V transposed)
//   vtl bf16-lo [bh][d][VTS]     : VT_ELEMS ushorts
#define WS_TENSOR ((size_t)Bn*Sn*Dn)          // 7,692,288
#define KV_ELEMS  ((size_t)BHn*Sn*HDn)        // 7,692,288 ushorts
#define VT_ELEMS  ((size_t)BHn*HDn*VTS)       // 7,766,016 ushorts
#define CTX_OFF   (WS_TENSOR)

// output element offsets (fp32), concatenated in return order:
// attention_output (16,626,768) | attention_probs (16,12,626,626) | contribution (16,12,626)
#define OUT1_OFF ((size_t)Bn*Sn*Dn)
#define OUT2_OFF (OUT1_OFF + (size_t)BHn*Sn*Sn)

typedef __attribute__((ext_vector_type(8))) short  s8b;   // 8 bf16 (4 VGPR)
typedef __attribute__((ext_vector_type(4))) float  f32x4; // MFMA acc

__device__ __forceinline__ ushort bf16h(float x) {
    uint u = __float_as_uint(x);
    return (ushort)((u + 0x7FFFu + ((u >> 16) & 1u)) >> 16);   // RNE
}
__device__ __forceinline__ float bf16f(ushort h) {
    return __uint_as_float(((uint)h) << 16);
}
__device__ __forceinline__ void split8(const float* __restrict__ x,
                                       s8b& hi, s8b& lo) {
#pragma unroll
    for (int e = 0; e < 8; ++e) {
        ushort h = bf16h(x[e]);
        hi[e] = (short)h;
        lo[e] = (short)bf16h(x[e] - bf16f(h));
    }
}

// ---------------------------------------------------------------------------
// Kernel 1: fused QKV projection.  C = hidden(M x 768) @ W(768 x 768) + b.
// z==0 -> Q f32 (bh,s,hd);  z==1 -> K bf16 hi/lo (bh,s,hd);
// z==2 -> V^T bf16 hi/lo (bh,hd,s) with row stride VTS.
// ---------------------------------------------------------------------------
__global__ __launch_bounds__(256) void qkv_gemm(
    const float* __restrict__ A,
    const float* __restrict__ Wq, const float* __restrict__ bq,
    const float* __restrict__ Wk, const float* __restrict__ bk,
    const float* __restrict__ Wv, const float* __restrict__ bv,
    float* __restrict__ ws)
{
    __shared__ float As[8][128];   // transposed: As[k][m]
    __shared__ float Bs[8][128];

    const int z = blockIdx.z;
    const float* __restrict__ W    = (z == 0) ? Wq : (z == 1) ? Wk : Wv;
    const float* __restrict__ bias = (z == 0) ? bq : (z == 1) ? bk : bv;

    float*  qout = ws;
    ushort* khp  = (ushort*)(ws + 2*WS_TENSOR);
    ushort* klp  = khp + KV_ELEMS;
    ushort* vthp = klp + KV_ELEMS;
    ushort* vtlp = vthp + VT_ELEMS;

    const int m0 = blockIdx.x * 128;
    const int n0 = blockIdx.y * 128;
    const int t  = threadIdx.x;
    const int tx = t & 15;
    const int ty = t >> 4;

    float acc[8][8];
#pragma unroll
    for (int i = 0; i < 8; ++i)
#pragma unroll
        for (int j = 0; j < 8; ++j) acc[i][j] = 0.f;

    const int a_m = t >> 1;
    const int a_k = (t & 1) * 4;
    const int b_k = t >> 5;
    const int b_n = (t & 31) * 4;
    const int arow = m0 + a_m;

    for (int k0 = 0; k0 < Dn; k0 += 8) {
        float4 av = make_float4(0.f, 0.f, 0.f, 0.f);
        if (arow < Mn) av = *(const float4*)(A + (size_t)arow*Dn + k0 + a_k);
        As[a_k+0][a_m] = av.x;
        As[a_k+1][a_m] = av.y;
        As[a_k+2][a_m] = av.z;
        As[a_k+3][a_m] = av.w;
        *(float4*)&Bs[b_k][b_n] =
            *(const float4*)(W + (size_t)(k0 + b_k)*Dn + n0 + b_n);
        __syncthreads();
#pragma unroll
        for (int kk = 0; kk < 8; ++kk) {
            float a[8], b[8];
            *(float4*)&a[0] = *(const float4*)&As[kk][ty*4];
            *(float4*)&a[4] = *(const float4*)&As[kk][64 + ty*4];
            *(float4*)&b[0] = *(const float4*)&Bs[kk][tx*4];
            *(float4*)&b[4] = *(const float4*)&Bs[kk][64 + tx*4];
#pragma unroll
            for (int i = 0; i < 8; ++i)
#pragma unroll
                for (int j = 0; j < 8; ++j)
                    acc[i][j] += a[i]*b[j];
        }
        __syncthreads();
    }

#pragma unroll
    for (int i = 0; i < 8; ++i) {
        int ml = (i < 4) ? (ty*4 + i) : (64 + ty*4 + i - 4);
        int m = m0 + ml;
        if (m >= Mn) continue;
        int bb = m / Sn;
        int s  = m - bb*Sn;
#pragma unroll
        for (int jg = 0; jg < 2; ++jg) {
            int nl = (jg == 0) ? (tx*4) : (64 + tx*4);
            int n  = n0 + nl;
            int h  = n >> 6;
            int hd = n & 63;
            float4 r;
            r.x = acc[i][jg*4+0] + bias[n+0];
            r.y = acc[i][jg*4+1] + bias[n+1];
            r.z = acc[i][jg*4+2] + bias[n+2];
            r.w = acc[i][jg*4+3] + bias[n+3];
            if (z == 0) {
                *(float4*)(qout + (((size_t)(bb*Hn + h)*Sn + s)*HDn + hd)) = r;
            } else if (z == 1) {
                ushort4 hu, lu;
                hu.x = bf16h(r.x); lu.x = bf16h(r.x - bf16f(hu.x));
                hu.y = bf16h(r.y); lu.y = bf16h(r.y - bf16f(hu.y));
                hu.z = bf16h(r.z); lu.z = bf16h(r.z - bf16f(hu.z));
                hu.w = bf16h(r.w); lu.w = bf16h(r.w - bf16f(hu.w));
                size_t o = ((size_t)(bb*Hn + h)*Sn + s)*HDn + hd;
                *(ushort4*)(khp + o) = hu;
                *(ushort4*)(klp + o) = lu;
            } else {
                float rv[4] = {r.x, r.y, r.z, r.w};
#pragma unroll
                for (int e = 0; e < 4; ++e) {
                    ushort hh = bf16h(rv[e]);
                    size_t o = ((size_t)(bb*Hn + h)*HDn + hd + e)*VTS + s;
                    vthp[o] = hh;
                    vtlp[o] = bf16h(rv[e] - bf16f(hh));
                }
            }
        }
    }
}

// ---------------------------------------------------------------------------
// Kernel 2: attention core (MFMA).  One block = one (b,h) x 16 query rows.
// grid = (bh, qtile) so all q-tiles of a head share an XCD's L2 for K/V.
// QK^T and P@V on v_mfma_f32_16x16x32_bf16 with split-bf16 fp32 emulation
// (3 MFMAs per product; rel err ~2^-16).  No K/V LDS staging at all.
// ---------------------------------------------------------------------------
__global__ __launch_bounds__(256, 4) void attn_kernel(
    const float* __restrict__ qws,
    const ushort* __restrict__ khp, const ushort* __restrict__ klp,
    const ushort* __restrict__ vthp, const ushort* __restrict__ vtlp,
    const int* __restrict__ mask,
    float* __restrict__ probs_out,
    float* __restrict__ ctxws, float* __restrict__ colws)
{
    __shared__ float sc[QT][SPAD];   // 16 x 644 scores -> probs (41.2 KB)
    __shared__ float red[256];       // row-0 fix reduction (1 KB)

    const int bh = blockIdx.x;
    const int bb = bh / Hn;
    const int q0 = blockIdx.y * QT;
    const int t  = threadIdx.x;
    const int w    = t >> 6;         // wave 0..3
    const int lane = t & 63;
    const int col  = lane & 15;      // A/B-frag row/col index
    const int g    = lane >> 4;      // lane group 0..3

    // ---- Q fragments (hoisted; reused across all key tiles) --------------
    // A-frag layout: lane holds A[row=lane&15][k=(lane>>4)*8 + j], j=0..7
    s8b qh0, ql0, qh1, ql1;
    {
        int qrow = q0 + col; if (qrow > Sn-1) qrow = Sn-1;
        const float* qp = qws + ((size_t)bh*Sn + qrow)*HDn;
        float x[8];
        *(float4*)&x[0] = *(const float4*)(qp + g*8);
        *(float4*)&x[4] = *(const float4*)(qp + g*8 + 4);
        split8(x, qh0, ql0);                       // k-step 0: d in [0,32)
        *(float4*)&x[0] = *(const float4*)(qp + 32 + g*8);
        *(float4*)&x[4] = *(const float4*)(qp + 32 + g*8 + 4);
        split8(x, qh1, ql1);                       // k-step 1: d in [32,64)
    }

    // ---- phase 1: scores = Q K^T / 8  (wave w owns keys kc+w*16..+15) ----
    for (int kc = 0; kc < 640; kc += 64) {
        int key  = kc + w*16 + col;
        int keyc = key > Sn-1 ? Sn-1 : key;        // clamp (finite data)
        const ushort* kb = khp + ((size_t)bh*Sn + keyc)*HDn + g*8;
        const ushort* lb = klp + ((size_t)bh*Sn + keyc)*HDn + g*8;
        s8b kh0 = *(const s8b*)(kb);
        s8b kh1 = *(const s8b*)(kb + 32);
        s8b kl0 = *(const s8b*)(lb);
        s8b kl1 = *(const s8b*)(lb + 32);
        f32x4 acc = {0.f, 0.f, 0.f, 0.f};
        acc = __builtin_amdgcn_mfma_f32_16x16x32_bf16(qh0, kh0, acc, 0, 0, 0);
        acc = __builtin_amdgcn_mfma_f32_16x16x32_bf16(ql0, kh0, acc, 0, 0, 0);
        acc = __builtin_amdgcn_mfma_f32_16x16x32_bf16(qh0, kl0, acc, 0, 0, 0);
        acc = __builtin_amdgcn_mfma_f32_16x16x32_bf16(qh1, kh1, acc, 0, 0, 0);
        acc = __builtin_amdgcn_mfma_f32_16x16x32_bf16(ql1, kh1, acc, 0, 0, 0);
        acc = __builtin_amdgcn_mfma_f32_16x16x32_bf16(qh1, kl1, acc, 0, 0, 0);
        // D layout (HW-verified): col = lane&15 (key), row = g*4+reg (q-row)
#pragma unroll
        for (int rr = 0; rr < 4; ++rr)
            sc[g*4 + rr][key] = acc[rr] * 0.125f;
    }
    __syncthreads();

    // ---- phase 2: row-0 adjustment (global q==0 lives in q-tile 0) ------
    if (blockIdx.y == 0) {
        float lm = -INFINITY;
        for (int k = t; k < Sn; k += 256) lm = fmaxf(lm, sc[0][k]);
        red[t] = lm;
        __syncthreads();
        for (int off = 128; off > 0; off >>= 1) {
            if (t < off) red[t] = fmaxf(red[t], red[t + off]);
            __syncthreads();
        }
        float addv = red[0] * 0.25f;   // COEFF_MAX
        for (int k = t; k < Sn; k += 256) {
            int mz = (k == 0) ? 0 : mask[(size_t)bb*(Sn-1) + k - 1];
            if (mz == 0) sc[0][k] += addv;
        }
        __syncthreads();
    }

    // col-0 extraction (post row-0 fix, pre softmax) for contribution
    if (t < QT) {
        int qq = q0 + t;
        if (qq < Sn) colws[(size_t)bh*Sn + qq] = sc[t][0];
    }
    __syncthreads();

    // ---- phase 3: row softmax, register-resident --------------------------
    const int r = t >> 4;
    const int j = t & 15;
    const int qr = q0 + r;
    {
        float2 rv[20];
        float lm = -INFINITY;
#pragma unroll
        for (int i = 0; i < 20; ++i) {
            int c = j*2 + i*32;
            float2 v = make_float2(-INFINITY, -INFINITY);
            if (c < Sn) v = *(const float2*)&sc[r][c];
            rv[i] = v;
            lm = fmaxf(lm, fmaxf(v.x, v.y));
        }
#pragma unroll
        for (int m = 8; m > 0; m >>= 1)
            lm = fmaxf(lm, __shfl_xor(lm, m, 16));

        float ls = 0.f;
#pragma unroll
        for (int i = 0; i < 20; ++i) {
            float ex = expf(rv[i].x - lm);
            float ey = expf(rv[i].y - lm);
            rv[i] = make_float2(ex, ey);
            ls += ex + ey;
        }
#pragma unroll
        for (int m = 8; m > 0; m >>= 1)
            ls += __shfl_xor(ls, m, 16);

        float inv = 1.0f / ls;
        float* orow = probs_out + ((size_t)bh*Sn + qr)*Sn;
#pragma unroll
        for (int i = 0; i < 20; ++i) {
            int c = j*2 + i*32;
            if (c < Sn) {
                float2 p = make_float2(rv[i].x * inv, rv[i].y * inv);
                *(float2*)&sc[r][c] = p;              // probs for PV
                if (qr < Sn) *(float2*)&orow[c] = p;  // coalesced chunks
            }
        }
    }
    // zero pad columns [Sn, 640) so phase-4 P-frags see p=0 there
    for (int idx = t; idx < QT * 14; idx += 256)
        sc[idx % QT][Sn + idx / QT] = 0.f;
    __syncthreads();

    // ---- phase 4: ctx^T = V^T @ P^T  (wave w owns d-rows w*16..+15) ------
    f32x4 accv = {0.f, 0.f, 0.f, 0.f};
    {
        const ushort* vb = vthp + ((size_t)bh*HDn + w*16 + col)*VTS;
        const ushort* wb = vtlp + ((size_t)bh*HDn + w*16 + col)*VTS;
        for (int k0 = 0; k0 < 640; k0 += 32) {
            s8b vh = *(const s8b*)(vb + k0 + g*8);   // may spill into next
            s8b vl = *(const s8b*)(wb + k0 + g*8);   // row; P=0 there.
            float p[8];
            *(float4*)&p[0] = *(const float4*)&sc[col][k0 + g*8];
            *(float4*)&p[4] = *(const float4*)&sc[col][k0 + g*8 + 4];
            s8b ph, pl;
            split8(p, ph, pl);
            accv = __builtin_amdgcn_mfma_f32_16x16x32_bf16(vh, ph, accv, 0, 0, 0);
            accv = __builtin_amdgcn_mfma_f32_16x16x32_bf16(vl, ph, accv, 0, 0, 0);
            accv = __builtin_amdgcn_mfma_f32_16x16x32_bf16(vh, pl, accv, 0, 0, 0);
        }
    }
    // D: col = lane&15 (q), row = g*4+reg (d-local) -> 4 consecutive d
    {
        int qq = q0 + col;
        if (qq < Sn)
            *(f32x4*)(ctxws + ((size_t)bh*Sn + qq)*HDn + w*16 + g*4) = accv;
    }
}

// ---------------------------------------------------------------------------
// Kernel 3: contribution = softmax over q of col-0 scores, IN PLACE in out2.
// ---------------------------------------------------------------------------
__global__ __launch_bounds__(256) void contrib_kernel(float* __restrict__ col)
{
    __shared__ float red[256];
    const int bh = blockIdx.x;
    const int t  = threadIdx.x;
    float* c = col + (size_t)bh*Sn;

    float lm = -INFINITY;
    for (int q = t; q < Sn; q += 256) lm = fmaxf(lm, c[q]);
    red[t] = lm;
    __syncthreads();
    for (int off = 128; off > 0; off >>= 1) {
        if (t < off) red[t] = fmaxf(red[t], red[t + off]);
        __syncthreads();
    }
    float mx = red[0];
    __syncthreads();
    float ls = 0.f;
    for (int q = t; q < Sn; q += 256) ls += expf(c[q] - mx);
    red[t] = ls;
    __syncthreads();
    for (int off = 128; off > 0; off >>= 1) {
        if (t < off) red[t] += red[t + off];
        __syncthreads();
    }
    float inv = 1.0f / red[0];
    for (int q = t; q < Sn; q += 256)
        c[q] = expf(c[q] - mx) * inv;    // in-place: each thread own q
}

// ---------------------------------------------------------------------------
// Kernel 4: attention_output = ctx @ Wo + bo  (fp32 in, fp32 out)
// ---------------------------------------------------------------------------
__global__ __launch_bounds__(256) void out_gemm(
    const float* __restrict__ ctx,
    const float* __restrict__ Wo, const float* __restrict__ bo,
    float* __restrict__ out0)
{
    __shared__ float As[8][128];
    __shared__ float Bs[8][128];

    const int m0 = blockIdx.x * 128;
    const int n0 = blockIdx.y * 128;
    const int t  = threadIdx.x;
    const int tx = t & 15;
    const int ty = t >> 4;

    float acc[8][8];
#pragma unroll
    for (int i = 0; i < 8; ++i)
#pragma unroll
        for (int j = 0; j < 8; ++j) acc[i][j] = 0.f;

    const int a_m = t >> 1;
    const int a_k = (t & 1) * 4;
    const int b_k = t >> 5;
    const int b_n = (t & 31) * 4;
    const int arow = m0 + a_m;
    int bb = 0, s = 0;
    if (arow < Mn) { bb = arow / Sn; s = arow - bb*Sn; }

    for (int k0 = 0; k0 < Dn; k0 += 8) {
        float4 av = make_float4(0.f, 0.f, 0.f, 0.f);
        if (arow < Mn) {
            int k = k0 + a_k;
            av = *(const float4*)(ctx +
                 (((size_t)(bb*Hn + (k >> 6))*Sn + s)*HDn + (k & 63)));
        }
        As[a_k+0][a_m] = av.x;
        As[a_k+1][a_m] = av.y;
        As[a_k+2][a_m] = av.z;
        As[a_k+3][a_m] = av.w;
        *(float4*)&Bs[b_k][b_n] =
            *(const float4*)(Wo + (size_t)(k0 + b_k)*Dn + n0 + b_n);
        __syncthreads();
#pragma unroll
        for (int kk = 0; kk < 8; ++kk) {
            float a[8], b[8];
            *(float4*)&a[0] = *(const float4*)&As[kk][ty*4];
            *(float4*)&a[4] = *(const float4*)&As[kk][64 + ty*4];
            *(float4*)&b[0] = *(const float4*)&Bs[kk][tx*4];
            *(float4*)&b[4] = *(const float4*)&Bs[kk][64 + tx*4];
#pragma unroll
            for (int i = 0; i < 8; ++i)
#pragma unroll
                for (int j = 0; j < 8; ++j)
                    acc[i][j] += a[i]*b[j];
        }
        __syncthreads();
    }

#pragma unroll
    for (int i = 0; i < 8; ++i) {
        int ml = (i < 4) ? (ty*4 + i) : (64 + ty*4 + i - 4);
        int m = m0 + ml;
        if (m >= Mn) continue;
#pragma unroll
        for (int jg = 0; jg < 2; ++jg) {
            int nl = (jg == 0) ? (tx*4) : (64 + tx*4);
            int n  = n0 + nl;
            float4 r;
            r.x = acc[i][jg*4+0] + bo[n+0];
            r.y = acc[i][jg*4+1] + bo[n+1];
            r.z = acc[i][jg*4+2] + bo[n+2];
            r.w = acc[i][jg*4+3] + bo[n+3];
            *(float4*)(out0 + (size_t)m*Dn + n) = r;
        }
    }
}

// ---------------------------------------------------------------------------
extern "C" void kernel_launch(void* const* d_in, const int* in_sizes, int n_in,
                              void* d_out, int out_size, void* d_ws, size_t ws_size,
                              hipStream_t stream)
{
    (void)in_sizes; (void)n_in; (void)out_size; (void)ws_size;
    const float* hidden = (const float*)d_in[0];
    const int*   mask   = (const int*)d_in[1];
    const float* Wq = (const float*)d_in[2];
    const float* bq = (const float*)d_in[3];
    const float* Wk = (const float*)d_in[4];
    const float* bk = (const float*)d_in[5];
    const float* Wv = (const float*)d_in[6];
    const float* bv = (const float*)d_in[7];
    const float* Wo = (const float*)d_in[8];
    const float* bo = (const float*)d_in[9];

    float* ws  = (float*)d_ws;
    float* out = (float*)d_out;

    float*  qws   = ws;
    float*  ctxws = ws + CTX_OFF;
    ushort* khp   = (ushort*)(ws + 2*WS_TENSOR);
    ushort* klp   = khp + KV_ELEMS;
    ushort* vthp  = klp + KV_ELEMS;
    ushort* vtlp  = vthp + VT_ELEMS;
    float*  colws = out + OUT2_OFF;   // raw col-0 scores; contrib in-place

    qkv_gemm<<<dim3((Mn + 127)/128, Dn/128, 3), 256, 0, stream>>>(
        hidden, Wq, bq, Wk, bk, Wv, bv, ws);

    attn_kernel<<<dim3(BHn, (Sn + QT - 1)/QT), 256, 0, stream>>>(
        qws, khp, klp, vthp, vtlp, mask, out + OUT1_OFF, ctxws, colws);

    contrib_kernel<<<BHn, 256, 0, stream>>>(colws);

    out_gemm<<<dim3((Mn + 127)/128, Dn/128), 256, 0, stream>>>(
        ctxws, Wo, bo, out);
}

// Round 5
// 950.790 us; speedup vs baseline: 16.0762x; 1.3262x over previous
//
#include <hip/hip_runtime.h>
#include <math.h>

#define Bn  16
#define Sn  626
#define Dn  768
#define Hn  12
#define HDn 64
#define Mn  (Bn*Sn)        // 10016
#define BHn (Bn*Hn)        // 192

#define QT   16
#define SPAD 644           // score tile column pad
#define VTS  632           // V^T row stride in ushorts

// ---------------- workspace layout (float offsets) -------------------------
// [0, WS_TENSOR)            : Q f32 [bh][s][64]   (after attn: Wo^T split scratch)
// [WS_TENSOR, 2*WS_TENSOR)  : CTX f32 [m][768]
// then ushort arrays at ws + 2*WS_TENSOR: kh, kl, vth, vtl
#define WS_TENSOR ((size_t)Bn*Sn*Dn)          // 7,692,288
#define KV_ELEMS  ((size_t)BHn*Sn*HDn)        // 7,692,288 ushorts
#define VT_ELEMS  ((size_t)BHn*HDn*VTS)       // 7,766,016 ushorts
#define CTX_OFF   (WS_TENSOR)
#define WELEMS    ((size_t)Dn*Dn)             // 589,824

// output element offsets (fp32), concatenated in return order:
// attention_output (16,626,768) | attention_probs (16,12,626,626) | contribution (16,12,626)
#define OUT1_OFF ((size_t)Bn*Sn*Dn)
#define OUT2_OFF (OUT1_OFF + (size_t)BHn*Sn*Sn)

typedef __attribute__((ext_vector_type(8))) short  s8b;   // 8 bf16 (4 VGPR)
typedef __attribute__((ext_vector_type(4))) float  f32x4; // MFMA acc

__device__ __forceinline__ ushort bf16h(float x) {
    uint u = __float_as_uint(x);
    return (ushort)((u + 0x7FFFu + ((u >> 16) & 1u)) >> 16);   // RNE
}
__device__ __forceinline__ float bf16f(ushort h) {
    return __uint_as_float(((uint)h) << 16);
}
__device__ __forceinline__ void split8(const float* __restrict__ x,
                                       s8b& hi, s8b& lo) {
#pragma unroll
    for (int e = 0; e < 8; ++e) {
        ushort h = bf16h(x[e]);
        hi[e] = (short)h;
        lo[e] = (short)bf16h(x[e] - bf16f(h));
    }
}

// ---------------------------------------------------------------------------
// Kernel 0: W -> W^T split (hi/lo bf16).  589,824 threads, one elem each.
// ---------------------------------------------------------------------------
__global__ __launch_bounds__(256) void wsplit_kernel(
    const float* __restrict__ W,
    ushort* __restrict__ dh, ushort* __restrict__ dl)
{
    int idx = blockIdx.x * 256 + threadIdx.x;       // coalesced read
    int k = idx / Dn, n = idx - k * Dn;
    float x = W[idx];
    ushort h = bf16h(x);
    dh[(size_t)n * Dn + k] = h;
    dl[(size_t)n * Dn + k] = bf16h(x - bf16f(h));
}

// ---------------------------------------------------------------------------
// Kernel 1: QKV projection on MFMA (split-bf16 fp32 emulation, 3 mfma/term).
// A split on the fly; W read pre-transposed+split.  128x128 tile, BK=32,
// 4 waves in 2x2 quadrants of 64x64, 4x4 frags each.
// z==0 -> Q f32 (bh,s,hd); z==1 -> K bf16 hi/lo; z==2 -> V^T bf16 hi/lo.
// ---------------------------------------------------------------------------
__global__ __launch_bounds__(256) void qkv_gemm(
    const float* __restrict__ A,
    const ushort* __restrict__ wsp,   // [z][hi|lo][WELEMS] W^T splits
    const float* __restrict__ bq, const float* __restrict__ bk,
    const float* __restrict__ bv,
    float* __restrict__ ws)
{
    __shared__ ushort Ah[128][40], Al[128][40];
    __shared__ ushort Bh[128][40], Bl[128][40];

    const int z = blockIdx.z;
    const float* __restrict__ bias = (z == 0) ? bq : (z == 1) ? bk : bv;
    const ushort* __restrict__ wth = wsp + (size_t)z * 2 * WELEMS;
    const ushort* __restrict__ wtl = wth + WELEMS;

    float*  qout = ws;
    ushort* khp  = (ushort*)(ws + 2*WS_TENSOR);
    ushort* klp  = khp + KV_ELEMS;
    ushort* vthp = klp + KV_ELEMS;
    ushort* vtlp = vthp + VT_ELEMS;

    const int m0 = blockIdx.x * 128;
    const int n0 = blockIdx.y * 128;
    const int t  = threadIdx.x;
    const int w    = t >> 6;
    const int lane = t & 63;
    const int col  = lane & 15;
    const int g    = lane >> 4;
    const int wm = w >> 1, wn = w & 1;

    const int sr = t >> 1;           // staging row 0..127
    const int sk = (t & 1) * 16;     // staging k-offset 0/16

    f32x4 acc[4][4];
#pragma unroll
    for (int i = 0; i < 4; ++i)
#pragma unroll
        for (int j = 0; j < 4; ++j) acc[i][j] = (f32x4){0.f, 0.f, 0.f, 0.f};

    const int arow = m0 + sr;
    for (int k0 = 0; k0 < Dn; k0 += 32) {
        // ---- stage A (fp32 -> split bf16) ----
        float x[16];
        if (arow < Mn) {
            const float* ap = A + (size_t)arow*Dn + k0 + sk;
            *(float4*)&x[0]  = *(const float4*)(ap);
            *(float4*)&x[4]  = *(const float4*)(ap + 4);
            *(float4*)&x[8]  = *(const float4*)(ap + 8);
            *(float4*)&x[12] = *(const float4*)(ap + 12);
        } else {
#pragma unroll
            for (int e = 0; e < 16; ++e) x[e] = 0.f;
        }
        {
            s8b h0, l0, h1, l1;
            split8(x, h0, l0);
            split8(x + 8, h1, l1);
            *(s8b*)&Ah[sr][sk]     = h0;
            *(s8b*)&Ah[sr][sk + 8] = h1;
            *(s8b*)&Al[sr][sk]     = l0;
            *(s8b*)&Al[sr][sk + 8] = l1;
        }
        // ---- stage W^T (already split) ----
        {
            const ushort* wp = wth + (size_t)(n0 + sr)*Dn + k0 + sk;
            const ushort* lp = wtl + (size_t)(n0 + sr)*Dn + k0 + sk;
            *(s8b*)&Bh[sr][sk]     = *(const s8b*)(wp);
            *(s8b*)&Bh[sr][sk + 8] = *(const s8b*)(wp + 8);
            *(s8b*)&Bl[sr][sk]     = *(const s8b*)(lp);
            *(s8b*)&Bl[sr][sk + 8] = *(const s8b*)(lp + 8);
        }
        __syncthreads();
        // ---- fragments + MFMA ----
        s8b ah[4], al[4], bh[4], bl[4];
#pragma unroll
        for (int i = 0; i < 4; ++i) {
            ah[i] = *(const s8b*)&Ah[wm*64 + i*16 + col][g*8];
            al[i] = *(const s8b*)&Al[wm*64 + i*16 + col][g*8];
        }
#pragma unroll
        for (int j = 0; j < 4; ++j) {
            bh[j] = *(const s8b*)&Bh[wn*64 + j*16 + col][g*8];
            bl[j] = *(const s8b*)&Bl[wn*64 + j*16 + col][g*8];
        }
#pragma unroll
        for (int i = 0; i < 4; ++i)
#pragma unroll
            for (int j = 0; j < 4; ++j) {
                acc[i][j] = __builtin_amdgcn_mfma_f32_16x16x32_bf16(ah[i], bh[j], acc[i][j], 0, 0, 0);
                acc[i][j] = __builtin_amdgcn_mfma_f32_16x16x32_bf16(al[i], bh[j], acc[i][j], 0, 0, 0);
                acc[i][j] = __builtin_amdgcn_mfma_f32_16x16x32_bf16(ah[i], bl[j], acc[i][j], 0, 0, 0);
            }
        __syncthreads();
    }

    // ---- epilogue: D col = lane&15 (n), row = g*4+reg (m within 16) ----
#pragma unroll
    for (int i = 0; i < 4; ++i) {
#pragma unroll
        for (int reg = 0; reg < 4; ++reg) {
            int m = m0 + wm*64 + i*16 + g*4 + reg;
            if (m >= Mn) continue;
            int bb = m / Sn;
            int s  = m - bb*Sn;
#pragma unroll
            for (int j = 0; j < 4; ++j) {
                int n  = n0 + wn*64 + j*16 + col;
                int h  = n >> 6;
                int hd = n & 63;
                float r = acc[i][j][reg] + bias[n];
                if (z == 0) {
                    qout[(((size_t)(bb*Hn + h)*Sn + s)*HDn + hd)] = r;
                } else if (z == 1) {
                    size_t o = ((size_t)(bb*Hn + h)*Sn + s)*HDn + hd;
                    ushort hh = bf16h(r);
                    khp[o] = hh;
                    klp[o] = bf16h(r - bf16f(hh));
                } else {
                    size_t o = ((size_t)(bb*Hn + h)*HDn + hd)*VTS + s;
                    ushort hh = bf16h(r);
                    vthp[o] = hh;
                    vtlp[o] = bf16h(r - bf16f(hh));
                }
            }
        }
    }
}

// ---------------------------------------------------------------------------
// Kernel 2: attention core (MFMA).  One block = one (b,h) x 16 query rows.
// ctx now written in [m][768] layout for the MFMA out_gemm.
// ---------------------------------------------------------------------------
__global__ __launch_bounds__(256, 4) void attn_kernel(
    const float* __restrict__ qws,
    const ushort* __restrict__ khp, const ushort* __restrict__ klp,
    const ushort* __restrict__ vthp, const ushort* __restrict__ vtlp,
    const int* __restrict__ mask,
    float* __restrict__ probs_out,
    float* __restrict__ ctxws, float* __restrict__ colws)
{
    __shared__ float sc[QT][SPAD];   // 16 x 644 scores -> probs (41.2 KB)
    __shared__ float red[256];

    const int bh = blockIdx.x;
    const int bb = bh / Hn;
    const int hh = bh - bb*Hn;
    const int q0 = blockIdx.y * QT;
    const int t  = threadIdx.x;
    const int w    = t >> 6;
    const int lane = t & 63;
    const int col  = lane & 15;
    const int g    = lane >> 4;

    // ---- Q fragments (hoisted) ----
    s8b qh0, ql0, qh1, ql1;
    {
        int qrow = q0 + col; if (qrow > Sn-1) qrow = Sn-1;
        const float* qp = qws + ((size_t)bh*Sn + qrow)*HDn;
        float x[8];
        *(float4*)&x[0] = *(const float4*)(qp + g*8);
        *(float4*)&x[4] = *(const float4*)(qp + g*8 + 4);
        split8(x, qh0, ql0);
        *(float4*)&x[0] = *(const float4*)(qp + 32 + g*8);
        *(float4*)&x[4] = *(const float4*)(qp + 32 + g*8 + 4);
        split8(x, qh1, ql1);
    }

    // ---- phase 1: scores = Q K^T / 8 ----
    for (int kc = 0; kc < 640; kc += 64) {
        int key  = kc + w*16 + col;
        int keyc = key > Sn-1 ? Sn-1 : key;
        const ushort* kb = khp + ((size_t)bh*Sn + keyc)*HDn + g*8;
        const ushort* lb = klp + ((size_t)bh*Sn + keyc)*HDn + g*8;
        s8b kh0 = *(const s8b*)(kb);
        s8b kh1 = *(const s8b*)(kb + 32);
        s8b kl0 = *(const s8b*)(lb);
        s8b kl1 = *(const s8b*)(lb + 32);
        f32x4 acc = {0.f, 0.f, 0.f, 0.f};
        acc = __builtin_amdgcn_mfma_f32_16x16x32_bf16(qh0, kh0, acc, 0, 0, 0);
        acc = __builtin_amdgcn_mfma_f32_16x16x32_bf16(ql0, kh0, acc, 0, 0, 0);
        acc = __builtin_amdgcn_mfma_f32_16x16x32_bf16(qh0, kl0, acc, 0, 0, 0);
        acc = __builtin_amdgcn_mfma_f32_16x16x32_bf16(qh1, kh1, acc, 0, 0, 0);
        acc = __builtin_amdgcn_mfma_f32_16x16x32_bf16(ql1, kh1, acc, 0, 0, 0);
        acc = __builtin_amdgcn_mfma_f32_16x16x32_bf16(qh1, kl1, acc, 0, 0, 0);
#pragma unroll
        for (int rr = 0; rr < 4; ++rr)
            sc[g*4 + rr][key] = acc[rr] * 0.125f;
    }
    __syncthreads();

    // ---- phase 2: row-0 adjustment ----
    if (blockIdx.y == 0) {
        float lm = -INFINITY;
        for (int k = t; k < Sn; k += 256) lm = fmaxf(lm, sc[0][k]);
        red[t] = lm;
        __syncthreads();
        for (int off = 128; off > 0; off >>= 1) {
            if (t < off) red[t] = fmaxf(red[t], red[t + off]);
            __syncthreads();
        }
        float addv = red[0] * 0.25f;   // COEFF_MAX
        for (int k = t; k < Sn; k += 256) {
            int mz = (k == 0) ? 0 : mask[(size_t)bb*(Sn-1) + k - 1];
            if (mz == 0) sc[0][k] += addv;
        }
        __syncthreads();
    }

    // col-0 extraction for contribution
    if (t < QT) {
        int qq = q0 + t;
        if (qq < Sn) colws[(size_t)bh*Sn + qq] = sc[t][0];
    }
    __syncthreads();

    // ---- phase 3: row softmax, register-resident ----
    const int r = t >> 4;
    const int j = t & 15;
    const int qr = q0 + r;
    {
        float2 rv[20];
        float lm = -INFINITY;
#pragma unroll
        for (int i = 0; i < 20; ++i) {
            int c = j*2 + i*32;
            float2 v = make_float2(-INFINITY, -INFINITY);
            if (c < Sn) v = *(const float2*)&sc[r][c];
            rv[i] = v;
            lm = fmaxf(lm, fmaxf(v.x, v.y));
        }
#pragma unroll
        for (int m = 8; m > 0; m >>= 1)
            lm = fmaxf(lm, __shfl_xor(lm, m, 16));

        float ls = 0.f;
#pragma unroll
        for (int i = 0; i < 20; ++i) {
            float ex = expf(rv[i].x - lm);
            float ey = expf(rv[i].y - lm);
            rv[i] = make_float2(ex, ey);
            ls += ex + ey;
        }
#pragma unroll
        for (int m = 8; m > 0; m >>= 1)
            ls += __shfl_xor(ls, m, 16);

        float inv = 1.0f / ls;
        float* orow = probs_out + ((size_t)bh*Sn + qr)*Sn;
#pragma unroll
        for (int i = 0; i < 20; ++i) {
            int c = j*2 + i*32;
            if (c < Sn) {
                float2 p = make_float2(rv[i].x * inv, rv[i].y * inv);
                *(float2*)&sc[r][c] = p;
                if (qr < Sn) *(float2*)&orow[c] = p;
            }
        }
    }
    // zero pad columns [Sn, 640)
    for (int idx = t; idx < QT * 14; idx += 256)
        sc[idx % QT][Sn + idx / QT] = 0.f;
    __syncthreads();

    // ---- phase 4: ctx^T = V^T @ P^T ----
    f32x4 accv = {0.f, 0.f, 0.f, 0.f};
    {
        const ushort* vb = vthp + ((size_t)bh*HDn + w*16 + col)*VTS;
        const ushort* wb = vtlp + ((size_t)bh*HDn + w*16 + col)*VTS;
        for (int k0 = 0; k0 < 640; k0 += 32) {
            s8b vh = *(const s8b*)(vb + k0 + g*8);
            s8b vl = *(const s8b*)(wb + k0 + g*8);
            float p[8];
            *(float4*)&p[0] = *(const float4*)&sc[col][k0 + g*8];
            *(float4*)&p[4] = *(const float4*)&sc[col][k0 + g*8 + 4];
            s8b ph, pl;
            split8(p, ph, pl);
            accv = __builtin_amdgcn_mfma_f32_16x16x32_bf16(vh, ph, accv, 0, 0, 0);
            accv = __builtin_amdgcn_mfma_f32_16x16x32_bf16(vl, ph, accv, 0, 0, 0);
            accv = __builtin_amdgcn_mfma_f32_16x16x32_bf16(vh, pl, accv, 0, 0, 0);
        }
    }
    // D: col = lane&15 (q), row = g*4+reg (d-local); ctx in [m][768] layout
    {
        int qq = q0 + col;
        if (qq < Sn)
            *(f32x4*)(ctxws + ((size_t)bb*Sn + qq)*Dn + hh*HDn + w*16 + g*4) = accv;
    }
}

// ---------------------------------------------------------------------------
// Kernel 3: contribution = softmax over q of col-0 scores, IN PLACE in out2.
// ---------------------------------------------------------------------------
__global__ __launch_bounds__(256) void contrib_kernel(float* __restrict__ col)
{
    __shared__ float red[256];
    const int bh = blockIdx.x;
    const int t  = threadIdx.x;
    float* c = col + (size_t)bh*Sn;

    float lm = -INFINITY;
    for (int q = t; q < Sn; q += 256) lm = fmaxf(lm, c[q]);
    red[t] = lm;
    __syncthreads();
    for (int off = 128; off > 0; off >>= 1) {
        if (t < off) red[t] = fmaxf(red[t], red[t + off]);
        __syncthreads();
    }
    float mx = red[0];
    __syncthreads();
    float ls = 0.f;
    for (int q = t; q < Sn; q += 256) ls += expf(c[q] - mx);
    red[t] = ls;
    __syncthreads();
    for (int off = 128; off > 0; off >>= 1) {
        if (t < off) red[t] += red[t + off];
        __syncthreads();
    }
    float inv = 1.0f / red[0];
    for (int q = t; q < Sn; q += 256)
        c[q] = expf(c[q] - mx) * inv;
}

// ---------------------------------------------------------------------------
// Kernel 4: attention_output = ctx @ Wo + bo on MFMA (split-bf16).
// ctx is [m][768] fp32; Wo^T split read from the dead Q workspace region.
// ---------------------------------------------------------------------------
__global__ __launch_bounds__(256) void out_gemm(
    const float* __restrict__ ctx,
    const ushort* __restrict__ woth,   // hi at 0, lo at +WELEMS
    const float* __restrict__ bo,
    float* __restrict__ out0)
{
    __shared__ ushort Ah[128][40], Al[128][40];
    __shared__ ushort Bh[128][40], Bl[128][40];

    const ushort* __restrict__ wotl = woth + WELEMS;

    const int m0 = blockIdx.x * 128;
    const int n0 = blockIdx.y * 128;
    const int t  = threadIdx.x;
    const int w    = t >> 6;
    const int lane = t & 63;
    const int col  = lane & 15;
    const int g    = lane >> 4;
    const int wm = w >> 1, wn = w & 1;

    const int sr = t >> 1;
    const int sk = (t & 1) * 16;

    f32x4 acc[4][4];
#pragma unroll
    for (int i = 0; i < 4; ++i)
#pragma unroll
        for (int j = 0; j < 4; ++j) acc[i][j] = (f32x4){0.f, 0.f, 0.f, 0.f};

    const int arow = m0 + sr;
    for (int k0 = 0; k0 < Dn; k0 += 32) {
        float x[16];
        if (arow < Mn) {
            const float* ap = ctx + (size_t)arow*Dn + k0 + sk;
            *(float4*)&x[0]  = *(const float4*)(ap);
            *(float4*)&x[4]  = *(const float4*)(ap + 4);
            *(float4*)&x[8]  = *(const float4*)(ap + 8);
            *(float4*)&x[12] = *(const float4*)(ap + 12);
        } else {
#pragma unroll
            for (int e = 0; e < 16; ++e) x[e] = 0.f;
        }
        {
            s8b h0, l0, h1, l1;
            split8(x, h0, l0);
            split8(x + 8, h1, l1);
            *(s8b*)&Ah[sr][sk]     = h0;
            *(s8b*)&Ah[sr][sk + 8] = h1;
            *(s8b*)&Al[sr][sk]     = l0;
            *(s8b*)&Al[sr][sk + 8] = l1;
        }
        {
            const ushort* wp = woth + (size_t)(n0 + sr)*Dn + k0 + sk;
            const ushort* lp = wotl + (size_t)(n0 + sr)*Dn + k0 + sk;
            *(s8b*)&Bh[sr][sk]     = *(const s8b*)(wp);
            *(s8b*)&Bh[sr][sk + 8] = *(const s8b*)(wp + 8);
            *(s8b*)&Bl[sr][sk]     = *(const s8b*)(lp);
            *(s8b*)&Bl[sr][sk + 8] = *(const s8b*)(lp + 8);
        }
        __syncthreads();
        s8b ah[4], al[4], bh[4], bl[4];
#pragma unroll
        for (int i = 0; i < 4; ++i) {
            ah[i] = *(const s8b*)&Ah[wm*64 + i*16 + col][g*8];
            al[i] = *(const s8b*)&Al[wm*64 + i*16 + col][g*8];
        }
#pragma unroll
        for (int j = 0; j < 4; ++j) {
            bh[j] = *(const s8b*)&Bh[wn*64 + j*16 + col][g*8];
            bl[j] = *(const s8b*)&Bl[wn*64 + j*16 + col][g*8];
        }
#pragma unroll
        for (int i = 0; i < 4; ++i)
#pragma unroll
            for (int j = 0; j < 4; ++j) {
                acc[i][j] = __builtin_amdgcn_mfma_f32_16x16x32_bf16(ah[i], bh[j], acc[i][j], 0, 0, 0);
                acc[i][j] = __builtin_amdgcn_mfma_f32_16x16x32_bf16(al[i], bh[j], acc[i][j], 0, 0, 0);
                acc[i][j] = __builtin_amdgcn_mfma_f32_16x16x32_bf16(ah[i], bl[j], acc[i][j], 0, 0, 0);
            }
        __syncthreads();
    }

#pragma unroll
    for (int i = 0; i < 4; ++i) {
#pragma unroll
        for (int reg = 0; reg < 4; ++reg) {
            int m = m0 + wm*64 + i*16 + g*4 + reg;
            if (m >= Mn) continue;
#pragma unroll
            for (int j = 0; j < 4; ++j) {
                int n = n0 + wn*64 + j*16 + col;
                out0[(size_t)m*Dn + n] = acc[i][j][reg] + bo[n];
            }
        }
    }
}

// ---------------------------------------------------------------------------
extern "C" void kernel_launch(void* const* d_in, const int* in_sizes, int n_in,
                              void* d_out, int out_size, void* d_ws, size_t ws_size,
                              hipStream_t stream)
{
    (void)in_sizes; (void)n_in; (void)out_size; (void)ws_size;
    const float* hidden = (const float*)d_in[0];
    const int*   mask   = (const int*)d_in[1];
    const float* Wq = (const float*)d_in[2];
    const float* bq = (const float*)d_in[3];
    const float* Wk = (const float*)d_in[4];
    const float* bk = (const float*)d_in[5];
    const float* Wv = (const float*)d_in[6];
    const float* bv = (const float*)d_in[7];
    const float* Wo = (const float*)d_in[8];
    const float* bo = (const float*)d_in[9];

    float* ws  = (float*)d_ws;
    float* out = (float*)d_out;

    float*  qws   = ws;
    float*  ctxws = ws + CTX_OFF;
    ushort* khp   = (ushort*)(ws + 2*WS_TENSOR);
    ushort* klp   = khp + KV_ELEMS;
    ushort* vthp  = klp + KV_ELEMS;
    ushort* vtlp  = vthp + VT_ELEMS;
    float*  colws = out + OUT2_OFF;       // raw col-0 scores; contrib in-place

    // W^T splits: Wq/Wk/Wv scratch in probs output region (overwritten by attn);
    // Wo scratch in Q workspace region (dead after attn).
    ushort* wsp  = (ushort*)(out + OUT1_OFF);
    ushort* wosp = (ushort*)ws;

    const int WG = (int)(WELEMS / 256);   // 2304
    wsplit_kernel<<<WG, 256, 0, stream>>>(Wq, wsp + 0*2*WELEMS, wsp + 0*2*WELEMS + WELEMS);
    wsplit_kernel<<<WG, 256, 0, stream>>>(Wk, wsp + 1*2*WELEMS, wsp + 1*2*WELEMS + WELEMS);
    wsplit_kernel<<<WG, 256, 0, stream>>>(Wv, wsp + 2*2*WELEMS, wsp + 2*2*WELEMS + WELEMS);

    qkv_gemm<<<dim3((Mn + 127)/128, Dn/128, 3), 256, 0, stream>>>(
        hidden, wsp, bq, bk, bv, ws);

    attn_kernel<<<dim3(BHn, (Sn + QT - 1)/QT), 256, 0, stream>>>(
        qws, khp, klp, vthp, vtlp, mask, out + OUT1_OFF, ctxws, colws);

    // Q region is dead now; reuse it for the Wo^T split.
    wsplit_kernel<<<WG, 256, 0, stream>>>(Wo, wosp, wosp + WELEMS);

    contrib_kernel<<<BHn, 256, 0, stream>>>(colws);

    out_gemm<<<dim3((Mn + 127)/128, Dn/128), 256, 0, stream>>>(
        ctxws, wosp, bo, out);
}